// Round 1
// baseline (296.184 us; speedup 1.0000x reference)
//
#include <hip/hip_runtime.h>

#define KS   11
#define PAD  5
#define TW   64
#define TH   16
#define IW   (TW + 2*PAD)   // 74
#define IH   (TH + 2*PAD)   // 26
#define IWP  76             // padded LDS stride for input tiles
#define HWDIM 512
#define IMG  (HWDIM*HWDIM)
#define PLANES 96           // 32 images * 3 channels
#define TILES_X 8
#define TILES_Y 32
#define TILES_PER_PLANE (TILES_X*TILES_Y)   // 256
#define PARTIALS_PER_IMG (3*TILES_PER_PLANE) // 768

__global__ __launch_bounds__(256) void ssim_tile_kernel(
    const float* __restrict__ pred,
    const float* __restrict__ target,
    const float* __restrict__ kern,
    float* __restrict__ partial)
{
    __shared__ float sP[IH][IWP];
    __shared__ float sT[IH][IWP];
    __shared__ float hp[5][IH][TW];
    __shared__ float red[4];

    const int tid   = threadIdx.x;
    const int tileX = blockIdx.x;   // 0..7
    const int tileY = blockIdx.y;   // 0..31
    const int plane = blockIdx.z;   // 0..95 = b*3 + c

    // Recover the exact 1D separable factors from the provided 2D kernel:
    // k2d[i][j] = a_i * a_j with sum(a)=1  =>  a_j = k2d[5][j] / sqrt(k2d[5][5])
    float w[KS];
    {
        const float inv_a5 = 1.0f / sqrtf(kern[5*KS + 5]);
        #pragma unroll
        for (int j = 0; j < KS; ++j) w[j] = kern[5*KS + j] * inv_a5;
    }

    const int rowStart = tileY * TH - PAD;
    const int colStart = tileX * TW - PAD;
    const float* pPlane = pred   + (size_t)plane * IMG;
    const float* tPlane = target + (size_t)plane * IMG;

    // ---- load halo'd tile, map x -> (x+1)/2, zero pad outside ----
    for (int idx = tid; idx < IH * IW; idx += 256) {
        const int r  = idx / IW;
        const int c  = idx - r * IW;
        const int gy = rowStart + r;
        const int gx = colStart + c;
        float pv = 0.0f, tv = 0.0f;
        if ((unsigned)gy < HWDIM && (unsigned)gx < HWDIM) {
            const int g = gy * HWDIM + gx;
            pv = (pPlane[g] + 1.0f) * 0.5f;
            tv = (tPlane[g] + 1.0f) * 0.5f;
        }
        sP[r][c] = pv;
        sT[r][c] = tv;
    }
    __syncthreads();

    // ---- horizontal separable pass over 5 fields ----
    for (int idx = tid; idx < IH * TW; idx += 256) {
        const int y = idx >> 6;     // /64
        const int x = idx & 63;
        float a0 = 0.f, a1 = 0.f, a2 = 0.f, a3 = 0.f, a4 = 0.f;
        #pragma unroll
        for (int k = 0; k < KS; ++k) {
            const float p  = sP[y][x + k];
            const float t  = sT[y][x + k];
            const float wk = w[k];
            a0 += wk * p;
            a1 += wk * t;
            a2 += wk * (p * p);
            a3 += wk * (t * t);
            a4 += wk * (p * t);
        }
        hp[0][y][x] = a0;
        hp[1][y][x] = a1;
        hp[2][y][x] = a2;
        hp[3][y][x] = a3;
        hp[4][y][x] = a4;
    }
    __syncthreads();

    // ---- vertical pass + SSIM map + local accumulation ----
    const float C1 = 1e-4f, C2 = 9e-4f, EPSV = 1e-8f;
    float lsum = 0.0f;
    for (int idx = tid; idx < TH * TW; idx += 256) {
        const int y = idx >> 6;
        const int x = idx & 63;
        float m0 = 0.f, m1 = 0.f, m2 = 0.f, m3 = 0.f, m4 = 0.f;
        #pragma unroll
        for (int k = 0; k < KS; ++k) {
            const float wk = w[k];
            m0 += wk * hp[0][y + k][x];
            m1 += wk * hp[1][y + k][x];
            m2 += wk * hp[2][y + k][x];
            m3 += wk * hp[3][y + k][x];
            m4 += wk * hp[4][y + k][x];
        }
        const float sx  = m2 - m0 * m0;
        const float sy  = m3 - m1 * m1;
        const float sxy = m4 - m0 * m1;
        const float num = (2.0f * m0 * m1 + C1) * (2.0f * sxy + C2);
        const float den = (m0 * m0 + m1 * m1 + C1) * (sx + sy + C2);
        lsum += num / (den + EPSV);
    }

    // ---- block reduction (wave64 shuffle tree, deterministic) ----
    #pragma unroll
    for (int off = 32; off > 0; off >>= 1)
        lsum += __shfl_down(lsum, off, 64);
    const int wave = tid >> 6;
    const int lane = tid & 63;
    if (lane == 0) red[wave] = lsum;
    __syncthreads();
    if (tid == 0) {
        const float bsum = red[0] + red[1] + red[2] + red[3];
        partial[(plane * TILES_Y + tileY) * TILES_X + tileX] = bsum;
    }
}

__global__ __launch_bounds__(256) void ssim_reduce_kernel(
    const float* __restrict__ partial,
    float* __restrict__ out)
{
    __shared__ float red[4];
    const int b   = blockIdx.x;     // image index 0..31
    const int tid = threadIdx.x;
    const float* p = partial + (size_t)b * PARTIALS_PER_IMG;

    float s = 0.0f;
    for (int i = tid; i < PARTIALS_PER_IMG; i += 256) s += p[i];

    #pragma unroll
    for (int off = 32; off > 0; off >>= 1)
        s += __shfl_down(s, off, 64);
    const int wave = tid >> 6;
    const int lane = tid & 63;
    if (lane == 0) red[wave] = s;
    __syncthreads();
    if (tid == 0) {
        const float total = red[0] + red[1] + red[2] + red[3];
        out[b] = total * (1.0f / (3.0f * 512.0f * 512.0f));
    }
}

extern "C" void kernel_launch(void* const* d_in, const int* in_sizes, int n_in,
                              void* d_out, int out_size, void* d_ws, size_t ws_size,
                              hipStream_t stream) {
    const float* pred   = (const float*)d_in[0];
    const float* target = (const float*)d_in[1];
    const float* kern   = (const float*)d_in[2];
    float* out     = (float*)d_out;
    float* partial = (float*)d_ws;   // needs 96*256*4 = 98304 bytes

    dim3 grid(TILES_X, TILES_Y, PLANES);
    ssim_tile_kernel<<<grid, 256, 0, stream>>>(pred, target, kern, partial);
    ssim_reduce_kernel<<<32, 256, 0, stream>>>(partial, out);
}

// Round 2
// 234.853 us; speedup vs baseline: 1.2611x; 1.2611x over previous
//
#include <hip/hip_runtime.h>

#define KS   11
#define PAD  5
#define TW   64
#define TH   32
#define IW   (TW + 2*PAD)   // 74
#define IH   (TH + 2*PAD)   // 42
#define IWP  76             // padded LDS row stride; 76*4=304 B = 19*16 -> float4-aligned rows
#define HWDIM 512
#define IMG  (HWDIM*HWDIM)
#define PLANES 96           // 32 images * 3 channels
#define TILES_X (HWDIM/TW)              // 8
#define TILES_Y (HWDIM/TH)              // 16
#define TILES_PER_PLANE (TILES_X*TILES_Y)    // 128
#define PARTIALS_PER_IMG (3*TILES_PER_PLANE) // 384

// Fields: u = p'+t', v = p'-t' with p'=(p+1)/2, t'=(t+1)/2.
//   mu_x*mu_y     = (mu_u^2 - mu_v^2)/4
//   mu_x^2+mu_y^2 = (mu_u^2 + mu_v^2)/2
//   conv(p'^2)+conv(t'^2) = (Su+Sv)/2,  conv(p't') = (Su-Sv)/4
// -> only 4 convolved fields needed: mu_u, mu_v, Su=conv(u^2), Sv=conv(v^2).

__global__ __launch_bounds__(256) void ssim_tile_kernel(
    const float* __restrict__ pred,
    const float* __restrict__ target,
    const float* __restrict__ kern,
    float* __restrict__ partial)
{
    __shared__ float sU[IH][IWP];
    __shared__ float sV[IH][IWP];
    __shared__ float hp[4][IH][TW];   // h-pass results, 4 fields
    __shared__ float red[4];

    const int tid   = threadIdx.x;
    const int tileX = blockIdx.x;   // 0..7
    const int tileY = blockIdx.y;   // 0..15
    const int plane = blockIdx.z;   // 0..95

    // exact 1D factors from the provided 2D kernel: a_j = k2d[5][j]/sqrt(k2d[5][5])
    float w[KS];
    {
        const float inv_a5 = 1.0f / sqrtf(kern[5*KS + 5]);
        #pragma unroll
        for (int j = 0; j < KS; ++j) w[j] = kern[5*KS + j] * inv_a5;
    }

    const int rowStart = tileY * TH - PAD;
    const int colStart = tileX * TW - PAD;
    const float* pPlane = pred   + (size_t)plane * IMG;
    const float* tPlane = target + (size_t)plane * IMG;

    // ---- stage u,v tile (halo'd, zero pad outside after the affine map) ----
    for (int idx = tid; idx < IH * IW; idx += 256) {
        const int r  = idx / IW;
        const int c  = idx - r * IW;
        const int gy = rowStart + r;
        const int gx = colStart + c;
        float u = 0.0f, v = 0.0f;
        if ((unsigned)gy < HWDIM && (unsigned)gx < HWDIM) {
            const int g = gy * HWDIM + gx;
            const float p = pPlane[g];
            const float t = tPlane[g];
            u = 0.5f * (p + t) + 1.0f;   // p' + t'
            v = 0.5f * (p - t);          // p' - t'
        }
        sU[r][c] = u;
        sV[r][c] = v;
    }
    __syncthreads();

    // ---- horizontal pass: 4-wide quads, b128 LDS traffic ----
    // 672 quads = IH(42) rows * 16 quads/row
    for (int q = tid; q < IH * (TW/4); q += 256) {
        const int row = q >> 4;
        const int x0  = (q & 15) << 2;

        float ru[16], rv[16], ru2[16], rv2[16];
        #pragma unroll
        for (int m = 0; m < 4; ++m) {
            const float4 a = *(const float4*)&sU[row][x0 + 4*m];
            ru[4*m+0]=a.x; ru[4*m+1]=a.y; ru[4*m+2]=a.z; ru[4*m+3]=a.w;
            const float4 b = *(const float4*)&sV[row][x0 + 4*m];
            rv[4*m+0]=b.x; rv[4*m+1]=b.y; rv[4*m+2]=b.z; rv[4*m+3]=b.w;
        }
        #pragma unroll
        for (int j = 0; j < 14; ++j) { ru2[j] = ru[j]*ru[j]; rv2[j] = rv[j]*rv[j]; }

        float a0[4] = {0,0,0,0}, a1[4] = {0,0,0,0};
        float a2[4] = {0,0,0,0}, a3[4] = {0,0,0,0};
        #pragma unroll
        for (int k = 0; k < KS; ++k) {
            const float wk = w[k];
            #pragma unroll
            for (int i = 0; i < 4; ++i) {
                a0[i] = fmaf(wk, ru [i+k], a0[i]);
                a1[i] = fmaf(wk, rv [i+k], a1[i]);
                a2[i] = fmaf(wk, ru2[i+k], a2[i]);
                a3[i] = fmaf(wk, rv2[i+k], a3[i]);
            }
        }
        *(float4*)&hp[0][row][x0] = make_float4(a0[0],a0[1],a0[2],a0[3]);
        *(float4*)&hp[1][row][x0] = make_float4(a1[0],a1[1],a1[2],a1[3]);
        *(float4*)&hp[2][row][x0] = make_float4(a2[0],a2[1],a2[2],a2[3]);
        *(float4*)&hp[3][row][x0] = make_float4(a3[0],a3[1],a3[2],a3[3]);
    }
    __syncthreads();

    // ---- vertical pass: thread owns 2 cols x 4 rows; each hp row read once ----
    const int dx = tid & 31;    // cols 2dx, 2dx+1
    const int dy = tid >> 5;    // 0..7 -> output rows 4dy..4dy+3
    const int r0 = dy * 4;

    float acc[4][4][2];         // [local row][field][col]
    #pragma unroll
    for (int i = 0; i < 4; ++i)
        #pragma unroll
        for (int f = 0; f < 4; ++f) { acc[i][f][0] = 0.0f; acc[i][f][1] = 0.0f; }

    #pragma unroll
    for (int j = 0; j < 14; ++j) {
        const int row = r0 + j;
        const float2 f0 = *(const float2*)&hp[0][row][2*dx];
        const float2 f1 = *(const float2*)&hp[1][row][2*dx];
        const float2 f2 = *(const float2*)&hp[2][row][2*dx];
        const float2 f3 = *(const float2*)&hp[3][row][2*dx];
        #pragma unroll
        for (int i = 0; i < 4; ++i) {
            const int k = j - i;              // compile-time after unroll
            if (0 <= k && k < KS) {
                const float wk = w[k];
                acc[i][0][0] = fmaf(wk, f0.x, acc[i][0][0]);
                acc[i][0][1] = fmaf(wk, f0.y, acc[i][0][1]);
                acc[i][1][0] = fmaf(wk, f1.x, acc[i][1][0]);
                acc[i][1][1] = fmaf(wk, f1.y, acc[i][1][1]);
                acc[i][2][0] = fmaf(wk, f2.x, acc[i][2][0]);
                acc[i][2][1] = fmaf(wk, f2.y, acc[i][2][1]);
                acc[i][3][0] = fmaf(wk, f3.x, acc[i][3][0]);
                acc[i][3][1] = fmaf(wk, f3.y, acc[i][3][1]);
            }
        }
    }

    // ---- SSIM map + local sum ----
    const float C1 = 1e-4f, C2 = 9e-4f, EPSV = 1e-8f;
    float lsum = 0.0f;
    #pragma unroll
    for (int i = 0; i < 4; ++i) {
        #pragma unroll
        for (int c = 0; c < 2; ++c) {
            const float mu_u = acc[i][0][c];
            const float mu_v = acc[i][1][c];
            const float Su   = acc[i][2][c];
            const float Sv   = acc[i][3][c];
            const float mu2d = 0.5f * (mu_u*mu_u - mu_v*mu_v); // 2 mux muy
            const float mu2s = 0.5f * (mu_u*mu_u + mu_v*mu_v); // mux^2+muy^2
            const float Sd   = 0.5f * (Su - Sv);               // 2 conv(p t)
            const float Ss   = 0.5f * (Su + Sv);               // conv(p^2)+conv(t^2)
            const float A = mu2d + C1;
            const float B = Sd - mu2d + C2;
            const float Cc = mu2s + C1;
            const float D  = Ss - mu2s + C2;
            lsum += A * B / (Cc * D + EPSV);
        }
    }

    // ---- block reduction ----
    #pragma unroll
    for (int off = 32; off > 0; off >>= 1)
        lsum += __shfl_down(lsum, off, 64);
    const int wave = tid >> 6;
    const int lane = tid & 63;
    if (lane == 0) red[wave] = lsum;
    __syncthreads();
    if (tid == 0) {
        const float bsum = red[0] + red[1] + red[2] + red[3];
        partial[(plane * TILES_Y + tileY) * TILES_X + tileX] = bsum;
    }
}

__global__ __launch_bounds__(256) void ssim_reduce_kernel(
    const float* __restrict__ partial,
    float* __restrict__ out)
{
    __shared__ float red[4];
    const int b   = blockIdx.x;   // 0..31
    const int tid = threadIdx.x;
    const float* p = partial + (size_t)b * PARTIALS_PER_IMG;

    float s = 0.0f;
    for (int i = tid; i < PARTIALS_PER_IMG; i += 256) s += p[i];

    #pragma unroll
    for (int off = 32; off > 0; off >>= 1)
        s += __shfl_down(s, off, 64);
    const int wave = tid >> 6;
    const int lane = tid & 63;
    if (lane == 0) red[wave] = s;
    __syncthreads();
    if (tid == 0) {
        const float total = red[0] + red[1] + red[2] + red[3];
        out[b] = total * (1.0f / (3.0f * 512.0f * 512.0f));
    }
}

extern "C" void kernel_launch(void* const* d_in, const int* in_sizes, int n_in,
                              void* d_out, int out_size, void* d_ws, size_t ws_size,
                              hipStream_t stream) {
    const float* pred   = (const float*)d_in[0];
    const float* target = (const float*)d_in[1];
    const float* kern   = (const float*)d_in[2];
    float* out     = (float*)d_out;
    float* partial = (float*)d_ws;   // 12288 * 4 B = 48 KiB

    dim3 grid(TILES_X, TILES_Y, PLANES);
    ssim_tile_kernel<<<grid, 256, 0, stream>>>(pred, target, kern, partial);
    ssim_reduce_kernel<<<32, 256, 0, stream>>>(partial, out);
}